// Round 1
// baseline (1545.182 us; speedup 1.0000x reference)
//
#include <hip/hip_runtime.h>
#include <hip/hip_bf16.h>
#include <stdint.h>

// ---------------------------------------------------------------------------
// Phi3-style transformer forward, MI355X round 2.
// B=1 S=2048 H=2048 NH=32 HD=64 I=8192 L=2.
// Round-2 change: QKV and W1 GEMMs moved to a 256x256 8-phase schedule
// (T2 XOR-swizzle + T3/T4 counted-vmcnt pipeline + T5 setprio), plain HIP.
// Wo/W2 (N=2048 -> only 64 blocks at 256^2) stay on the verified 128^2 kernel.
// ---------------------------------------------------------------------------

#define H_   2048
#define NH_  32
#define HD_  64
#define I_   8192
#define L_   2
#define S_   2048
#define EPS_ 1e-5f

typedef _Float16 f16;
typedef __attribute__((ext_vector_type(8))) _Float16 f16x8;
typedef __attribute__((ext_vector_type(4))) float   f32x4;

#define BF16_PROBE 0x3F803F80u

static __device__ __forceinline__ float bf2f(unsigned short b) {
  return __uint_as_float(((unsigned int)b) << 16);
}

static __device__ __forceinline__ float gelu_f(float x) {
  float y = 0.7978845608028654f * x * (1.0f + 0.044715f * x * x);
  return x / (1.0f + __expf(-2.0f * y));
}

// async global->LDS, 16B per lane.  LDS dest must be wave-base + lane*16.
#define GLDS(gp, lp)                                                          \
  __builtin_amdgcn_global_load_lds(                                           \
      (const __attribute__((address_space(1))) unsigned int*)(gp),            \
      (__attribute__((address_space(3))) unsigned int*)(lp), 16, 0, 0)

// ---------------------------------------------------------------------------
// embeds (bf16 or fp32 per probe) -> fp32 residual
__global__ __launch_bounds__(256) void embed2f_k(const void* __restrict__ e,
                                                 float* __restrict__ xf,
                                                 const unsigned int* __restrict__ probe) {
  bool isbf = (*probe == BF16_PROBE);
  int i = (blockIdx.x * 256 + threadIdx.x) * 4;
  float4 o;
  if (isbf) {
    uint2 d = *(const uint2*)((const unsigned short*)e + i);
    o.x = bf2f((unsigned short)(d.x & 0xffff));
    o.y = bf2f((unsigned short)(d.x >> 16));
    o.z = bf2f((unsigned short)(d.y & 0xffff));
    o.w = bf2f((unsigned short)(d.y >> 16));
  } else {
    o = *(const float4*)((const float*)e + i);
  }
  *(float4*)(xf + i) = o;
}

// ---------------------------------------------------------------------------
// LayerNorm (mean-subtract, var-normalize, *gamma, no beta) over H=2048.
template <int OUT_FINAL>
__global__ __launch_bounds__(256) void ln_k(const float* __restrict__ x,
                                            const void* __restrict__ gammav,
                                            size_t geoff,
                                            void* __restrict__ outv,
                                            const unsigned int* __restrict__ probe) {
  bool isbf = (*probe == BF16_PROBE);
  int row = blockIdx.x, t = threadIdx.x;
  const float* xr = x + (size_t)row * H_;
  float4 a = ((const float4*)xr)[t];
  float4 b = ((const float4*)xr)[t + 256];
  float s  = a.x + a.y + a.z + a.w + b.x + b.y + b.z + b.w;
  float ss = a.x*a.x + a.y*a.y + a.z*a.z + a.w*a.w
           + b.x*b.x + b.y*b.y + b.z*b.z + b.w*b.w;
#pragma unroll
  for (int m = 32; m >= 1; m >>= 1) { s += __shfl_xor(s, m); ss += __shfl_xor(ss, m); }
  __shared__ float red[8];
  if ((t & 63) == 0) { red[t >> 6] = s; red[4 + (t >> 6)] = ss; }
  __syncthreads();
  s  = red[0] + red[1] + red[2] + red[3];
  ss = red[4] + red[5] + red[6] + red[7];
  float mu   = s * (1.0f / H_);
  float rstd = rsqrtf(ss * (1.0f / H_) - mu * mu + EPS_);
  float va[8] = {a.x, a.y, a.z, a.w, b.x, b.y, b.z, b.w};
#pragma unroll
  for (int hh = 0; hh < 2; ++hh) {
    int cbase = (hh == 0) ? t * 4 : (t + 256) * 4;
#pragma unroll
    for (int j = 0; j < 4; ++j) {
      int c = cbase + j;
      float g = isbf ? bf2f(((const unsigned short*)gammav)[geoff + c])
                     : ((const float*)gammav)[geoff + c];
      float o = (va[hh * 4 + j] - mu) * rstd * g;
      size_t idx = (size_t)row * H_ + c;
      if (OUT_FINAL) {
        if (isbf) ((__hip_bfloat16*)outv)[idx] = __float2bfloat16(o);
        else      ((float*)outv)[idx] = o;
      } else {
        ((f16*)outv)[idx] = (f16)o;
      }
    }
  }
}

// ---------------------------------------------------------------------------
// Transpose + convert: W[R,C] (bf16|fp32) -> Wt[C,R] f16.  64x64 tiles.
__global__ __launch_bounds__(256) void transp_k(const void* __restrict__ in,
                                                size_t eoff,
                                                f16* __restrict__ out, int R, int C,
                                                const unsigned int* __restrict__ probe) {
  bool isbf = (*probe == BF16_PROBE);
  __shared__ __attribute__((aligned(16))) f16 tile[64][72];  // +8 pad
  int t = threadIdx.x;
  int r0 = blockIdx.y * 64, c0 = blockIdx.x * 64;
#pragma unroll
  for (int it = 0; it < 2; ++it) {
    int idx = it * 256 + t;
    int r = idx >> 3, c8 = (idx & 7) * 8;
    size_t goff = eoff + (size_t)(r0 + r) * C + c0 + c8;
    if (isbf) {
      uint4 d = *(const uint4*)((const unsigned short*)in + goff);  // 8 bf16
      unsigned int dw[4] = {d.x, d.y, d.z, d.w};
#pragma unroll
      for (int p = 0; p < 4; ++p) {
        tile[r][c8 + 2 * p]     = (f16)bf2f((unsigned short)(dw[p] & 0xffff));
        tile[r][c8 + 2 * p + 1] = (f16)bf2f((unsigned short)(dw[p] >> 16));
      }
    } else {
      float4 fa = *(const float4*)((const float*)in + goff);
      float4 fb = *(const float4*)((const float*)in + goff + 4);
      tile[r][c8 + 0] = (f16)fa.x; tile[r][c8 + 1] = (f16)fa.y;
      tile[r][c8 + 2] = (f16)fa.z; tile[r][c8 + 3] = (f16)fa.w;
      tile[r][c8 + 4] = (f16)fb.x; tile[r][c8 + 5] = (f16)fb.y;
      tile[r][c8 + 6] = (f16)fb.z; tile[r][c8 + 7] = (f16)fb.w;
    }
  }
  __syncthreads();
#pragma unroll
  for (int it = 0; it < 2; ++it) {
    int idx = it * 256 + t;
    int rn = idx >> 3, k8 = (idx & 7) * 8;
    f16x8 o;
#pragma unroll
    for (int j = 0; j < 8; ++j) o[j] = tile[k8 + j][rn];
    *(f16x8*)(out + (size_t)(c0 + rn) * R + r0 + k8) = o;
  }
}

// ---------------------------------------------------------------------------
// GEMM 128x128 (m97 structure): kept for Wo / W2 (N=2048 -> 256 blocks).
// MODE 2: xres += C + bias.
template <int MODE>
__global__ __launch_bounds__(256) void gemm_k(const f16* __restrict__ A,
                                              const f16* __restrict__ Bt,
                                              f16* __restrict__ Cf,
                                              float* __restrict__ xres,
                                              const void* __restrict__ biasv,
                                              size_t beoff,
                                              int N, int K,
                                              const unsigned int* __restrict__ probe) {
  __shared__ __attribute__((aligned(16))) f16 As[128 * 32];
  __shared__ __attribute__((aligned(16))) f16 Bs[128 * 32];
  int t = threadIdx.x;
  int lane = t & 63, w = t >> 6;
  int col = lane & 15, quad = lane >> 4;
  int tm = blockIdx.x * 128, tn = blockIdx.y * 128;
  int wm = (w & 1) * 64, wn = (w >> 1) * 64;

  f32x4 acc[4][4];
#pragma unroll
  for (int i = 0; i < 4; ++i)
#pragma unroll
    for (int j = 0; j < 4; ++j) acc[i][j] = (f32x4){0.f, 0.f, 0.f, 0.f};

  const f16* Ab = A  + (size_t)(tm + (t >> 2)) * K + (t & 3) * 8;
  const f16* Bb = Bt + (size_t)(tn + (t >> 2)) * K + (t & 3) * 8;
  f16* Al = As + t * 8;
  f16* Bl = Bs + t * 8;

  for (int k0 = 0; k0 < K; k0 += 32) {
    GLDS(Ab + k0, Al);
    GLDS(Ab + (size_t)64 * K + k0, Al + 2048);
    GLDS(Bb + k0, Bl);
    GLDS(Bb + (size_t)64 * K + k0, Bl + 2048);
    __syncthreads();
    f16x8 af[4], bf[4];
#pragma unroll
    for (int i = 0; i < 4; ++i)
      af[i] = *(const f16x8*)(As + (wm + i * 16 + col) * 32 + quad * 8);
#pragma unroll
    for (int j = 0; j < 4; ++j)
      bf[j] = *(const f16x8*)(Bs + (wn + j * 16 + col) * 32 + quad * 8);
#pragma unroll
    for (int i = 0; i < 4; ++i)
#pragma unroll
      for (int j = 0; j < 4; ++j)
        acc[i][j] = __builtin_amdgcn_mfma_f32_16x16x32_f16(af[i], bf[j], acc[i][j], 0, 0, 0);
    __syncthreads();
  }

  bool isbf = false;
  if (MODE == 2) isbf = (*probe == BF16_PROBE);
#pragma unroll
  for (int i = 0; i < 4; ++i) {
    int row = tm + wm + i * 16 + quad * 4;
#pragma unroll
    for (int j = 0; j < 4; ++j) {
      int cg = tn + wn + j * 16 + col;
#pragma unroll
      for (int r = 0; r < 4; ++r) {
        float v = acc[i][j][r];
        if (MODE == 1) v = gelu_f(v);
        if (MODE <= 1) {
          Cf[(size_t)(row + r) * N + cg] = (f16)v;
        } else {
          float bb = isbf ? bf2f(((const unsigned short*)biasv)[beoff + cg])
                          : ((const float*)biasv)[beoff + cg];
          size_t idx = (size_t)(row + r) * N + cg;
          xres[idx] += v + bb;
        }
      }
    }
  }
}

// ---------------------------------------------------------------------------
// GEMM 256x256, BK=64, 8 waves (2Mx4N), 8-phase counted-vmcnt schedule.
// LDS 128 KiB: [buf2][A|B][256][64] f16, 16B-granule XOR swizzle g^=(row&7)
// (linear global_load_lds dest + inverse-swizzled GLOBAL source + swizzled
//  ds_read -- both-sides involution, rule 21).
// Staging schedule (region free-times verified):
//   ph0: A0(u+1)  ph1: A1(u+1)  ph2: B0(u+2)  ph3: B1(u+2)
// Boundary wait once per K-tile at ph3: vmcnt(4) (2 half-tiles in flight).
// MODE 0: store f16.  MODE 1: gelu -> f16.
// Requires: M%256==0, N%256==0, K%64==0, K/64 >= 2.

#define MIDBAR()                                                              \
  asm volatile("" ::: "memory");                                              \
  __builtin_amdgcn_s_barrier();                                               \
  asm volatile("s_waitcnt lgkmcnt(0)" ::: "memory");                          \
  __builtin_amdgcn_sched_barrier(0);                                          \
  __builtin_amdgcn_s_setprio(1)

#define ENDBAR()                                                              \
  asm volatile("" ::: "memory");                                              \
  __builtin_amdgcn_s_barrier();                                               \
  __builtin_amdgcn_sched_barrier(0)

#define LDA8(AF, BUF, MH)                                                     \
  _Pragma("unroll") for (int m2 = 0; m2 < 4; ++m2)                            \
  _Pragma("unroll") for (int kk = 0; kk < 2; ++kk)                            \
    AF[m2][kk] = *(const f16x8*)(lds + (BUF) * 32768 +                        \
        (wr * 128 + (MH) * 64 + m2 * 16 + col) * 64 +                         \
        ((((kk << 2) + quad) ^ xq) << 3));

#define LDB4(BF, BUF, NH)                                                     \
  _Pragma("unroll") for (int n2 = 0; n2 < 2; ++n2)                            \
  _Pragma("unroll") for (int kk = 0; kk < 2; ++kk)                            \
    BF[n2][kk] = *(const f16x8*)(lds + 16384 + (BUF) * 32768 +                \
        (wc * 64 + (NH) * 32 + n2 * 16 + col) * 64 +                         \
        ((((kk << 2) + quad) ^ xq) << 3));

#define QMM(AF, BF, MH, NH)                                                   \
  _Pragma("unroll") for (int m2 = 0; m2 < 4; ++m2)                            \
  _Pragma("unroll") for (int n2 = 0; n2 < 2; ++n2)                            \
  _Pragma("unroll") for (int kk = 0; kk < 2; ++kk)                            \
    acc[(MH) * 4 + m2][(NH) * 2 + n2] =                                       \
        __builtin_amdgcn_mfma_f32_16x16x32_f16(                               \
            AF[m2][kk], BF[n2][kk], acc[(MH) * 4 + m2][(NH) * 2 + n2], 0, 0, 0);

template <int MODE>
__global__ __launch_bounds__(512, 2) void gemm256_k(const f16* __restrict__ A,
                                                    const f16* __restrict__ Bt,
                                                    f16* __restrict__ Cf,
                                                    int N, int K) {
  __shared__ __attribute__((aligned(16))) f16 lds[65536];  // 128 KiB
  const int t = threadIdx.x;
  const int lane = t & 63, wid = t >> 6;
  const int col = lane & 15, quad = lane >> 4;
  const int xq = lane & 7;
  const int wr = wid >> 2, wc = wid & 3;  // 2M x 4N waves
  const int tm = blockIdx.x * 256, tn = blockIdx.y * 256;
  const int NK = K >> 6;

  f32x4 acc[8][4];
#pragma unroll
  for (int i = 0; i < 8; ++i)
#pragma unroll
    for (int j = 0; j < 4; ++j) acc[i][j] = (f32x4){0.f, 0.f, 0.f, 0.f};

  // per-thread staging geometry (j-independent swizzled source granule)
  const int srow = t >> 3;                       // 0..63
  const int gs   = (t & 7) ^ (srow & 7);         // inverse-swizzled src granule
  const f16* gA = A  + (size_t)(tm + srow) * K + gs * 8;
  const f16* gB = Bt + (size_t)(tn + srow) * K + gs * 8;
  f16* lbase = lds + t * 8;

  // stage half-tile (mat: 0=A 1=B, half h) of K-tile u; 2 x GLDS per thread
  auto STAGE = [&](int mat, int h, int u) {
    if (u >= NK) return;
    const f16* gp0 = (mat ? gB : gA) + (size_t)(h * 128) * K + u * 64;
    f16* lp = lbase + (u & 1) * 32768 + mat * 16384 + h * 8192;
    GLDS(gp0, lp);
    GLDS(gp0 + (size_t)64 * K, lp + 4096);
  };

  // prologue: B0(0),B1(0),A0(0),A1(0),B0(1),B1(1); tile0 resident after wait
  STAGE(1, 0, 0); STAGE(1, 1, 0); STAGE(0, 0, 0); STAGE(0, 1, 0);
  STAGE(1, 0, 1); STAGE(1, 1, 1);
  asm volatile("s_waitcnt vmcnt(4)" ::: "memory");
  __builtin_amdgcn_s_barrier();
  __builtin_amdgcn_sched_barrier(0);

  f16x8 afr[4][2], b0f[2][2], b1f[2][2];

  for (int u = 0; u < NK; ++u) {
    const int b = u & 1;
    // ---- phase 0: Q(0,0); reads A-mh0 (8) + B-nh0 (4); stage A0(u+1)
    LDA8(afr, b, 0);
    LDB4(b0f, b, 0);
    STAGE(0, 0, u + 1);
    MIDBAR();
    QMM(afr, b0f, 0, 0);
    __builtin_amdgcn_s_setprio(0);
    ENDBAR();
    // ---- phase 1: Q(0,1); reads B-nh1 (4); stage A1(u+1)
    LDB4(b1f, b, 1);
    STAGE(0, 1, u + 1);
    MIDBAR();
    QMM(afr, b1f, 0, 1);
    __builtin_amdgcn_s_setprio(0);
    ENDBAR();
    // ---- phase 2: Q(1,1); reads A-mh1 (8); stage B0(u+2)
    LDA8(afr, b, 1);
    STAGE(1, 0, u + 2);
    MIDBAR();
    QMM(afr, b1f, 1, 1);
    __builtin_amdgcn_s_setprio(0);
    ENDBAR();
    // ---- phase 3: Q(1,0); no reads (b0f kept in regs); stage B1(u+2)
    STAGE(1, 1, u + 2);
    MIDBAR();
    QMM(afr, b0f, 1, 0);
    __builtin_amdgcn_s_setprio(0);
    if (u + 2 < NK) { asm volatile("s_waitcnt vmcnt(4)" ::: "memory"); }
    else            { asm volatile("s_waitcnt vmcnt(0)" ::: "memory"); }
    ENDBAR();
  }

  // epilogue: C/D layout col=lane&15, row=quad*4+reg (m89/m91 verified)
#pragma unroll
  for (int m = 0; m < 8; ++m) {
    int row = tm + wr * 128 + m * 16 + quad * 4;
#pragma unroll
    for (int n = 0; n < 4; ++n) {
      int cg = tn + wc * 64 + n * 16 + col;
#pragma unroll
      for (int r = 0; r < 4; ++r) {
        float v = acc[m][n][r];
        if (MODE == 1) v = gelu_f(v);
        Cf[(size_t)(row + r) * N + cg] = (f16)v;
      }
    }
  }
}

// ---------------------------------------------------------------------------
// Fused causal flash attention.  qkv:[S, 3H] f16.
__global__ __launch_bounds__(256) void attn_k(const f16* __restrict__ qkv,
                                              f16* __restrict__ ctx) {
  __shared__ __attribute__((aligned(16))) f16 Ks[64 * 72];
  __shared__ __attribute__((aligned(16))) f16 Vt[64 * 72];
  __shared__ __attribute__((aligned(16))) f16 Ps[4 * 16 * 72];
  const int RS = 3 * H_;
  int t = threadIdx.x, w = t >> 6, lane = t & 63;
  int col = lane & 15, quad = lane >> 4;
  int head = blockIdx.y;
  int qt = (gridDim.x - 1) - blockIdx.x;
  int q0 = qt * 64;

  int qrow = q0 + w * 16 + col;
  const f16* qp = qkv + (size_t)qrow * RS + head * HD_ + quad * 8;
  f16x8 qf0 = *(const f16x8*)qp;
  f16x8 qf1 = *(const f16x8*)(qp + 32);

  f32x4 O[4];
#pragma unroll
  for (int ht = 0; ht < 4; ++ht) O[ht] = (f32x4){0.f, 0.f, 0.f, 0.f};
  f32x4 mrow = (f32x4){-1e30f, -1e30f, -1e30f, -1e30f};
  f32x4 lrow = (f32x4){0.f, 0.f, 0.f, 0.f};
  f16* pw = Ps + w * 16 * 72;

  for (int c = 0; c <= qt; ++c) {
    int k0 = c * 64;
#pragma unroll
    for (int it = 0; it < 2; ++it) {
      int idx = it * 256 + t;
      int r = idx >> 3, c8 = (idx & 7) * 8;
      const f16* kp = qkv + (size_t)(k0 + r) * RS + H_ + head * HD_ + c8;
      *(f16x8*)(Ks + r * 72 + c8) = *(const f16x8*)kp;
      const f16* vp = qkv + (size_t)(k0 + r) * RS + 2 * H_ + head * HD_ + c8;
      f16x8 vv = *(const f16x8*)vp;
#pragma unroll
      for (int j = 0; j < 8; ++j) Vt[(c8 + j) * 72 + r] = vv[j];
    }
    __syncthreads();

    f32x4 s[4];
#pragma unroll
    for (int nt = 0; nt < 4; ++nt) {
      const f16* kb = Ks + (nt * 16 + col) * 72 + quad * 8;
      f16x8 b0 = *(const f16x8*)kb;
      f16x8 b1 = *(const f16x8*)(kb + 32);
      f32x4 z = (f32x4){0.f, 0.f, 0.f, 0.f};
      z = __builtin_amdgcn_mfma_f32_16x16x32_f16(qf0, b0, z, 0, 0, 0);
      z = __builtin_amdgcn_mfma_f32_16x16x32_f16(qf1, b1, z, 0, 0, 0);
      s[nt] = z;
    }
    int rq = q0 + w * 16 + quad * 4;
#pragma unroll
    for (int nt = 0; nt < 4; ++nt)
#pragma unroll
      for (int r = 0; r < 4; ++r) {
        float sv = s[nt][r] * 0.125f;
        if (k0 + nt * 16 + col > rq + r) sv = -1e30f;
        s[nt][r] = sv;
      }
    f32x4 mx;
#pragma unroll
    for (int r = 0; r < 4; ++r)
      mx[r] = fmaxf(fmaxf(s[0][r], s[1][r]), fmaxf(s[2][r], s[3][r]));
#pragma unroll
    for (int m = 1; m <= 8; m <<= 1)
#pragma unroll
      for (int r = 0; r < 4; ++r) mx[r] = fmaxf(mx[r], __shfl_xor(mx[r], m));
    f32x4 mnew, alpha, rs;
#pragma unroll
    for (int r = 0; r < 4; ++r) {
      mnew[r]  = fmaxf(mrow[r], mx[r]);
      alpha[r] = __expf(mrow[r] - mnew[r]);
      rs[r] = 0.f;
    }
#pragma unroll
    for (int nt = 0; nt < 4; ++nt)
#pragma unroll
      for (int r = 0; r < 4; ++r) {
        float p = __expf(s[nt][r] - mnew[r]);
        s[nt][r] = p;
        rs[r] += p;
      }
#pragma unroll
    for (int m = 1; m <= 8; m <<= 1)
#pragma unroll
      for (int r = 0; r < 4; ++r) rs[r] += __shfl_xor(rs[r], m);
#pragma unroll
    for (int r = 0; r < 4; ++r) {
      lrow[r] = lrow[r] * alpha[r] + rs[r];
      mrow[r] = mnew[r];
    }
#pragma unroll
    for (int ht = 0; ht < 4; ++ht)
#pragma unroll
      for (int r = 0; r < 4; ++r) O[ht][r] *= alpha[r];

#pragma unroll
    for (int nt = 0; nt < 4; ++nt)
#pragma unroll
      for (int r = 0; r < 4; ++r)
        pw[(quad * 4 + r) * 72 + nt * 16 + col] = (f16)s[nt][r];
    const f16* pr = pw + col * 72 + quad * 8;
    f16x8 p0 = *(const f16x8*)pr;
    f16x8 p1 = *(const f16x8*)(pr + 32);
#pragma unroll
    for (int ht = 0; ht < 4; ++ht) {
      const f16* vb = Vt + (ht * 16 + col) * 72 + quad * 8;
      f16x8 v0 = *(const f16x8*)vb;
      f16x8 v1 = *(const f16x8*)(vb + 32);
      O[ht] = __builtin_amdgcn_mfma_f32_16x16x32_f16(p0, v0, O[ht], 0, 0, 0);
      O[ht] = __builtin_amdgcn_mfma_f32_16x16x32_f16(p1, v1, O[ht], 0, 0, 0);
    }
    __syncthreads();
  }

#pragma unroll
  for (int ht = 0; ht < 4; ++ht)
#pragma unroll
    for (int r = 0; r < 4; ++r) {
      int row = q0 + w * 16 + quad * 4 + r;
      int cg = head * HD_ + ht * 16 + col;
      ctx[(size_t)row * H_ + cg] = (f16)(O[ht][r] / lrow[r]);
    }
}

// ---------------------------------------------------------------------------
extern "C" void kernel_launch(void* const* d_in, const int* in_sizes, int n_in,
                              void* d_out, int out_size, void* d_ws, size_t ws_size,
                              hipStream_t stream) {
  const void* embeds = d_in[0];
  const void* Wq = d_in[2];
  const void* Wk = d_in[3];
  const void* Wv = d_in[4];
  const void* Wo = d_in[5];
  const void* bo = d_in[6];
  const void* W1 = d_in[7];
  const void* W2 = d_in[8];
  const void* b2 = d_in[9];
  const void* g1 = d_in[10];
  const void* g2 = d_in[11];
  const void* gf = d_in[12];
  const unsigned int* probe = (const unsigned int*)g1;

  char* W = (char*)d_ws;
  float* xf  = (float*)(W);                       // 16 MB fp32 residual
  f16* hbuf  = (f16*)(W + (16ull << 20));         //  8 MB LN output
  f16* qkvb  = (f16*)(W + (24ull << 20));         // 24 MB fused q|k|v (attn)
  f16* ctxb  = (f16*)(W + (48ull << 20));         //  8 MB attention out
  f16* m1b   = (f16*)(W + (24ull << 20));         // 32 MB MLP mid (aliases)
  f16* Wt    = (f16*)(W + (56ull << 20));         // 32 MB transposed weight
  (void)in_sizes; (void)n_in; (void)out_size; (void)ws_size;

  embed2f_k<<<S_ * H_ / 1024, 256, 0, stream>>>(embeds, xf, probe);

  for (int l = 0; l < L_; ++l) {
    size_t wo = (size_t)l * H_ * H_;
    // --- attention block ---
    ln_k<0><<<S_, 256, 0, stream>>>(xf, g1, (size_t)l * H_, hbuf, probe);
    transp_k<<<dim3(H_ / 64, H_ / 64), 256, 0, stream>>>(Wq, wo, Wt, H_, H_, probe);
    transp_k<<<dim3(H_ / 64, H_ / 64), 256, 0, stream>>>(Wk, wo, Wt + (size_t)H_ * H_, H_, H_, probe);
    transp_k<<<dim3(H_ / 64, H_ / 64), 256, 0, stream>>>(Wv, wo, Wt + 2ull * H_ * H_, H_, H_, probe);
    gemm256_k<0><<<dim3(S_ / 256, 3 * H_ / 256), 512, 0, stream>>>(hbuf, Wt, qkvb, 3 * H_, H_);
    attn_k<<<dim3(S_ / 64, NH_), 256, 0, stream>>>(qkvb, ctxb);
    transp_k<<<dim3(H_ / 64, H_ / 64), 256, 0, stream>>>(Wo, wo, Wt, H_, H_, probe);
    gemm_k<2><<<dim3(S_ / 128, H_ / 128), 256, 0, stream>>>(ctxb, Wt, nullptr, xf, bo, (size_t)l * H_, H_, H_, probe);
    // --- MLP block ---
    ln_k<0><<<S_, 256, 0, stream>>>(xf, g2, (size_t)l * H_, hbuf, probe);
    transp_k<<<dim3(I_ / 64, H_ / 64), 256, 0, stream>>>(W1, (size_t)l * H_ * I_, Wt, H_, I_, probe);
    gemm256_k<1><<<dim3(S_ / 256, I_ / 256), 512, 0, stream>>>(hbuf, Wt, m1b, I_, H_);
    transp_k<<<dim3(H_ / 64, I_ / 64), 256, 0, stream>>>(W2, (size_t)l * I_ * H_, Wt, I_, H_, probe);
    gemm_k<2><<<dim3(S_ / 128, H_ / 128), 256, 0, stream>>>(m1b, Wt, nullptr, xf, b2, (size_t)l * H_, H_, I_, probe);
  }
  ln_k<1><<<S_, 256, 0, stream>>>(xf, gf, 0, d_out, probe);
}

// Round 2
// 1522.199 us; speedup vs baseline: 1.0151x; 1.0151x over previous
//
#include <hip/hip_runtime.h>
#include <hip/hip_bf16.h>
#include <stdint.h>

// ---------------------------------------------------------------------------
// Phi3-style transformer forward, MI355X round 3.
// B=1 S=2048 H=2048 NH=32 HD=64 I=8192 L=2.
// Round-3 change: Wo and W2 GEMMs (were 128^2 2-barrier kernel, 193us @ 14%
// MfmaUtil, 11% occupancy = grid-starved 1 wave/SIMD) moved to the 256^2
// 8-phase counted-vmcnt kernel with split-K x4 (grid.z) + fp32 atomicAdd
// into the residual.  Bias added by split 0.  128^2 kernel deleted.
// ---------------------------------------------------------------------------

#define H_   2048
#define NH_  32
#define HD_  64
#define I_   8192
#define L_   2
#define S_   2048
#define EPS_ 1e-5f

typedef _Float16 f16;
typedef __attribute__((ext_vector_type(8))) _Float16 f16x8;
typedef __attribute__((ext_vector_type(4))) float   f32x4;

#define BF16_PROBE 0x3F803F80u

static __device__ __forceinline__ float bf2f(unsigned short b) {
  return __uint_as_float(((unsigned int)b) << 16);
}

static __device__ __forceinline__ float gelu_f(float x) {
  float y = 0.7978845608028654f * x * (1.0f + 0.044715f * x * x);
  return x / (1.0f + __expf(-2.0f * y));
}

// async global->LDS, 16B per lane.  LDS dest must be wave-base + lane*16.
#define GLDS(gp, lp)                                                          \
  __builtin_amdgcn_global_load_lds(                                           \
      (const __attribute__((address_space(1))) unsigned int*)(gp),            \
      (__attribute__((address_space(3))) unsigned int*)(lp), 16, 0, 0)

// ---------------------------------------------------------------------------
// embeds (bf16 or fp32 per probe) -> fp32 residual
__global__ __launch_bounds__(256) void embed2f_k(const void* __restrict__ e,
                                                 float* __restrict__ xf,
                                                 const unsigned int* __restrict__ probe) {
  bool isbf = (*probe == BF16_PROBE);
  int i = (blockIdx.x * 256 + threadIdx.x) * 4;
  float4 o;
  if (isbf) {
    uint2 d = *(const uint2*)((const unsigned short*)e + i);
    o.x = bf2f((unsigned short)(d.x & 0xffff));
    o.y = bf2f((unsigned short)(d.x >> 16));
    o.z = bf2f((unsigned short)(d.y & 0xffff));
    o.w = bf2f((unsigned short)(d.y >> 16));
  } else {
    o = *(const float4*)((const float*)e + i);
  }
  *(float4*)(xf + i) = o;
}

// ---------------------------------------------------------------------------
// LayerNorm (mean-subtract, var-normalize, *gamma, no beta) over H=2048.
template <int OUT_FINAL>
__global__ __launch_bounds__(256) void ln_k(const float* __restrict__ x,
                                            const void* __restrict__ gammav,
                                            size_t geoff,
                                            void* __restrict__ outv,
                                            const unsigned int* __restrict__ probe) {
  bool isbf = (*probe == BF16_PROBE);
  int row = blockIdx.x, t = threadIdx.x;
  const float* xr = x + (size_t)row * H_;
  float4 a = ((const float4*)xr)[t];
  float4 b = ((const float4*)xr)[t + 256];
  float s  = a.x + a.y + a.z + a.w + b.x + b.y + b.z + b.w;
  float ss = a.x*a.x + a.y*a.y + a.z*a.z + a.w*a.w
           + b.x*b.x + b.y*b.y + b.z*b.z + b.w*b.w;
#pragma unroll
  for (int m = 32; m >= 1; m >>= 1) { s += __shfl_xor(s, m); ss += __shfl_xor(ss, m); }
  __shared__ float red[8];
  if ((t & 63) == 0) { red[t >> 6] = s; red[4 + (t >> 6)] = ss; }
  __syncthreads();
  s  = red[0] + red[1] + red[2] + red[3];
  ss = red[4] + red[5] + red[6] + red[7];
  float mu   = s * (1.0f / H_);
  float rstd = rsqrtf(ss * (1.0f / H_) - mu * mu + EPS_);
  float va[8] = {a.x, a.y, a.z, a.w, b.x, b.y, b.z, b.w};
#pragma unroll
  for (int hh = 0; hh < 2; ++hh) {
    int cbase = (hh == 0) ? t * 4 : (t + 256) * 4;
#pragma unroll
    for (int j = 0; j < 4; ++j) {
      int c = cbase + j;
      float g = isbf ? bf2f(((const unsigned short*)gammav)[geoff + c])
                     : ((const float*)gammav)[geoff + c];
      float o = (va[hh * 4 + j] - mu) * rstd * g;
      size_t idx = (size_t)row * H_ + c;
      if (OUT_FINAL) {
        if (isbf) ((__hip_bfloat16*)outv)[idx] = __float2bfloat16(o);
        else      ((float*)outv)[idx] = o;
      } else {
        ((f16*)outv)[idx] = (f16)o;
      }
    }
  }
}

// ---------------------------------------------------------------------------
// Transpose + convert: W[R,C] (bf16|fp32) -> Wt[C,R] f16.  64x64 tiles.
__global__ __launch_bounds__(256) void transp_k(const void* __restrict__ in,
                                                size_t eoff,
                                                f16* __restrict__ out, int R, int C,
                                                const unsigned int* __restrict__ probe) {
  bool isbf = (*probe == BF16_PROBE);
  __shared__ __attribute__((aligned(16))) f16 tile[64][72];  // +8 pad
  int t = threadIdx.x;
  int r0 = blockIdx.y * 64, c0 = blockIdx.x * 64;
#pragma unroll
  for (int it = 0; it < 2; ++it) {
    int idx = it * 256 + t;
    int r = idx >> 3, c8 = (idx & 7) * 8;
    size_t goff = eoff + (size_t)(r0 + r) * C + c0 + c8;
    if (isbf) {
      uint4 d = *(const uint4*)((const unsigned short*)in + goff);  // 8 bf16
      unsigned int dw[4] = {d.x, d.y, d.z, d.w};
#pragma unroll
      for (int p = 0; p < 4; ++p) {
        tile[r][c8 + 2 * p]     = (f16)bf2f((unsigned short)(dw[p] & 0xffff));
        tile[r][c8 + 2 * p + 1] = (f16)bf2f((unsigned short)(dw[p] >> 16));
      }
    } else {
      float4 fa = *(const float4*)((const float*)in + goff);
      float4 fb = *(const float4*)((const float*)in + goff + 4);
      tile[r][c8 + 0] = (f16)fa.x; tile[r][c8 + 1] = (f16)fa.y;
      tile[r][c8 + 2] = (f16)fa.z; tile[r][c8 + 3] = (f16)fa.w;
      tile[r][c8 + 4] = (f16)fb.x; tile[r][c8 + 5] = (f16)fb.y;
      tile[r][c8 + 6] = (f16)fb.z; tile[r][c8 + 7] = (f16)fb.w;
    }
  }
  __syncthreads();
#pragma unroll
  for (int it = 0; it < 2; ++it) {
    int idx = it * 256 + t;
    int rn = idx >> 3, k8 = (idx & 7) * 8;
    f16x8 o;
#pragma unroll
    for (int j = 0; j < 8; ++j) o[j] = tile[k8 + j][rn];
    *(f16x8*)(out + (size_t)(c0 + rn) * R + r0 + k8) = o;
  }
}

// ---------------------------------------------------------------------------
// GEMM 256x256, BK=64, 8 waves (2Mx4N), 8-phase counted-vmcnt schedule.
// LDS 128 KiB: [buf2][A|B][256][64] f16, 16B-granule XOR swizzle g^=(row&7)
// (linear global_load_lds dest + inverse-swizzled GLOBAL source + swizzled
//  ds_read -- both-sides involution, rule 21).
// Staging schedule: ph0: A0(u+1)  ph1: A1(u+1)  ph2: B0(u+2)  ph3: B1(u+2)
// Boundary wait once per K-tile at ph3: vmcnt(4) (2 half-tiles in flight).
// MODE 0: store f16.  MODE 1: gelu -> f16.
// MODE 2: split-K partial; atomicAdd into fp32 residual (+bias on split 0).
// Requires: M%256==0, N%256==0, (K/gridDim.z)%64==0, (K/gridDim.z)/64 >= 2.

#define MIDBAR()                                                              \
  asm volatile("" ::: "memory");                                              \
  __builtin_amdgcn_s_barrier();                                               \
  asm volatile("s_waitcnt lgkmcnt(0)" ::: "memory");                          \
  __builtin_amdgcn_sched_barrier(0);                                          \
  __builtin_amdgcn_s_setprio(1)

#define ENDBAR()                                                              \
  asm volatile("" ::: "memory");                                              \
  __builtin_amdgcn_s_barrier();                                               \
  __builtin_amdgcn_sched_barrier(0)

#define LDA8(AF, BUF, MH)                                                     \
  _Pragma("unroll") for (int m2 = 0; m2 < 4; ++m2)                            \
  _Pragma("unroll") for (int kk = 0; kk < 2; ++kk)                            \
    AF[m2][kk] = *(const f16x8*)(lds + (BUF) * 32768 +                        \
        (wr * 128 + (MH) * 64 + m2 * 16 + col) * 64 +                         \
        ((((kk << 2) + quad) ^ xq) << 3));

#define LDB4(BF, BUF, NH)                                                     \
  _Pragma("unroll") for (int n2 = 0; n2 < 2; ++n2)                            \
  _Pragma("unroll") for (int kk = 0; kk < 2; ++kk)                            \
    BF[n2][kk] = *(const f16x8*)(lds + 16384 + (BUF) * 32768 +                \
        (wc * 64 + (NH) * 32 + n2 * 16 + col) * 64 +                         \
        ((((kk << 2) + quad) ^ xq) << 3));

#define QMM(AF, BF, MH, NH)                                                   \
  _Pragma("unroll") for (int m2 = 0; m2 < 4; ++m2)                            \
  _Pragma("unroll") for (int n2 = 0; n2 < 2; ++n2)                            \
  _Pragma("unroll") for (int kk = 0; kk < 2; ++kk)                            \
    acc[(MH) * 4 + m2][(NH) * 2 + n2] =                                       \
        __builtin_amdgcn_mfma_f32_16x16x32_f16(                               \
            AF[m2][kk], BF[n2][kk], acc[(MH) * 4 + m2][(NH) * 2 + n2], 0, 0, 0);

template <int MODE>
__global__ __launch_bounds__(512, 2) void gemm256_k(const f16* __restrict__ A,
                                                    const f16* __restrict__ Bt,
                                                    f16* __restrict__ Cf,
                                                    float* __restrict__ xres,
                                                    const void* __restrict__ biasv,
                                                    size_t beoff,
                                                    int N, int K,
                                                    const unsigned int* __restrict__ probe) {
  __shared__ __attribute__((aligned(16))) f16 lds[65536];  // 128 KiB
  const int t = threadIdx.x;
  const int lane = t & 63, wid = t >> 6;
  const int col = lane & 15, quad = lane >> 4;
  const int xq = lane & 7;
  const int wr = wid >> 2, wc = wid & 3;  // 2M x 4N waves
  const int tm = blockIdx.x * 256, tn = blockIdx.y * 256;
  const int KSP = K / (int)gridDim.z;       // K-range per split
  const int kb  = (int)blockIdx.z * KSP;    // this split's K offset
  const int NK  = KSP >> 6;

  f32x4 acc[8][4];
#pragma unroll
  for (int i = 0; i < 8; ++i)
#pragma unroll
    for (int j = 0; j < 4; ++j) acc[i][j] = (f32x4){0.f, 0.f, 0.f, 0.f};

  // per-thread staging geometry (inverse-swizzled source granule)
  const int srow = t >> 3;                       // 0..63
  const int gs   = (t & 7) ^ (srow & 7);         // inverse-swizzled src granule
  const f16* gA = A  + (size_t)(tm + srow) * K + kb + gs * 8;
  const f16* gB = Bt + (size_t)(tn + srow) * K + kb + gs * 8;
  f16* lbase = lds + t * 8;

  // stage half-tile (mat: 0=A 1=B, half h) of K-tile u; 2 x GLDS per thread
  auto STAGE = [&](int mat, int h, int u) {
    if (u >= NK) return;
    const f16* gp0 = (mat ? gB : gA) + (size_t)(h * 128) * K + u * 64;
    f16* lp = lbase + (u & 1) * 32768 + mat * 16384 + h * 8192;
    GLDS(gp0, lp);
    GLDS(gp0 + (size_t)64 * K, lp + 4096);
  };

  // prologue: B0(0),B1(0),A0(0),A1(0),B0(1),B1(1); tile0 resident after wait
  STAGE(1, 0, 0); STAGE(1, 1, 0); STAGE(0, 0, 0); STAGE(0, 1, 0);
  STAGE(1, 0, 1); STAGE(1, 1, 1);
  asm volatile("s_waitcnt vmcnt(4)" ::: "memory");
  __builtin_amdgcn_s_barrier();
  __builtin_amdgcn_sched_barrier(0);

  f16x8 afr[4][2], b0f[2][2], b1f[2][2];

  for (int u = 0; u < NK; ++u) {
    const int b = u & 1;
    // ---- phase 0: Q(0,0); reads A-mh0 (8) + B-nh0 (4); stage A0(u+1)
    LDA8(afr, b, 0);
    LDB4(b0f, b, 0);
    STAGE(0, 0, u + 1);
    MIDBAR();
    QMM(afr, b0f, 0, 0);
    __builtin_amdgcn_s_setprio(0);
    ENDBAR();
    // ---- phase 1: Q(0,1); reads B-nh1 (4); stage A1(u+1)
    LDB4(b1f, b, 1);
    STAGE(0, 1, u + 1);
    MIDBAR();
    QMM(afr, b1f, 0, 1);
    __builtin_amdgcn_s_setprio(0);
    ENDBAR();
    // ---- phase 2: Q(1,1); reads A-mh1 (8); stage B0(u+2)
    LDA8(afr, b, 1);
    STAGE(1, 0, u + 2);
    MIDBAR();
    QMM(afr, b1f, 1, 1);
    __builtin_amdgcn_s_setprio(0);
    ENDBAR();
    // ---- phase 3: Q(1,0); no reads (b0f kept in regs); stage B1(u+2)
    STAGE(1, 1, u + 2);
    MIDBAR();
    QMM(afr, b0f, 1, 0);
    __builtin_amdgcn_s_setprio(0);
    if (u + 2 < NK) { asm volatile("s_waitcnt vmcnt(4)" ::: "memory"); }
    else            { asm volatile("s_waitcnt vmcnt(0)" ::: "memory"); }
    ENDBAR();
  }

  // epilogue: C/D layout col=lane&15, row=quad*4+reg (m89/m91 verified)
  bool isbf = false;
  if (MODE == 2) isbf = (*probe == BF16_PROBE);
  const bool addb = (MODE == 2) && (blockIdx.z == 0);
#pragma unroll
  for (int m = 0; m < 8; ++m) {
    int row = tm + wr * 128 + m * 16 + quad * 4;
#pragma unroll
    for (int n = 0; n < 4; ++n) {
      int cg = tn + wc * 64 + n * 16 + col;
#pragma unroll
      for (int r = 0; r < 4; ++r) {
        float v = acc[m][n][r];
        if (MODE == 1) v = gelu_f(v);
        size_t idx = (size_t)(row + r) * N + cg;
        if (MODE <= 1) {
          Cf[idx] = (f16)v;
        } else {
          if (addb) {
            v += isbf ? bf2f(((const unsigned short*)biasv)[beoff + cg])
                      : ((const float*)biasv)[beoff + cg];
          }
          atomicAdd(xres + idx, v);
        }
      }
    }
  }
}

// ---------------------------------------------------------------------------
// Fused causal flash attention.  qkv:[S, 3H] f16.
__global__ __launch_bounds__(256) void attn_k(const f16* __restrict__ qkv,
                                              f16* __restrict__ ctx) {
  __shared__ __attribute__((aligned(16))) f16 Ks[64 * 72];
  __shared__ __attribute__((aligned(16))) f16 Vt[64 * 72];
  __shared__ __attribute__((aligned(16))) f16 Ps[4 * 16 * 72];
  const int RS = 3 * H_;
  int t = threadIdx.x, w = t >> 6, lane = t & 63;
  int col = lane & 15, quad = lane >> 4;
  int head = blockIdx.y;
  int qt = (gridDim.x - 1) - blockIdx.x;
  int q0 = qt * 64;

  int qrow = q0 + w * 16 + col;
  const f16* qp = qkv + (size_t)qrow * RS + head * HD_ + quad * 8;
  f16x8 qf0 = *(const f16x8*)qp;
  f16x8 qf1 = *(const f16x8*)(qp + 32);

  f32x4 O[4];
#pragma unroll
  for (int ht = 0; ht < 4; ++ht) O[ht] = (f32x4){0.f, 0.f, 0.f, 0.f};
  f32x4 mrow = (f32x4){-1e30f, -1e30f, -1e30f, -1e30f};
  f32x4 lrow = (f32x4){0.f, 0.f, 0.f, 0.f};
  f16* pw = Ps + w * 16 * 72;

  for (int c = 0; c <= qt; ++c) {
    int k0 = c * 64;
#pragma unroll
    for (int it = 0; it < 2; ++it) {
      int idx = it * 256 + t;
      int r = idx >> 3, c8 = (idx & 7) * 8;
      const f16* kp = qkv + (size_t)(k0 + r) * RS + H_ + head * HD_ + c8;
      *(f16x8*)(Ks + r * 72 + c8) = *(const f16x8*)kp;
      const f16* vp = qkv + (size_t)(k0 + r) * RS + 2 * H_ + head * HD_ + c8;
      f16x8 vv = *(const f16x8*)vp;
#pragma unroll
      for (int j = 0; j < 8; ++j) Vt[(c8 + j) * 72 + r] = vv[j];
    }
    __syncthreads();

    f32x4 s[4];
#pragma unroll
    for (int nt = 0; nt < 4; ++nt) {
      const f16* kb = Ks + (nt * 16 + col) * 72 + quad * 8;
      f16x8 b0 = *(const f16x8*)kb;
      f16x8 b1 = *(const f16x8*)(kb + 32);
      f32x4 z = (f32x4){0.f, 0.f, 0.f, 0.f};
      z = __builtin_amdgcn_mfma_f32_16x16x32_f16(qf0, b0, z, 0, 0, 0);
      z = __builtin_amdgcn_mfma_f32_16x16x32_f16(qf1, b1, z, 0, 0, 0);
      s[nt] = z;
    }
    int rq = q0 + w * 16 + quad * 4;
#pragma unroll
    for (int nt = 0; nt < 4; ++nt)
#pragma unroll
      for (int r = 0; r < 4; ++r) {
        float sv = s[nt][r] * 0.125f;
        if (k0 + nt * 16 + col > rq + r) sv = -1e30f;
        s[nt][r] = sv;
      }
    f32x4 mx;
#pragma unroll
    for (int r = 0; r < 4; ++r)
      mx[r] = fmaxf(fmaxf(s[0][r], s[1][r]), fmaxf(s[2][r], s[3][r]));
#pragma unroll
    for (int m = 1; m <= 8; m <<= 1)
#pragma unroll
      for (int r = 0; r < 4; ++r) mx[r] = fmaxf(mx[r], __shfl_xor(mx[r], m));
    f32x4 mnew, alpha, rs;
#pragma unroll
    for (int r = 0; r < 4; ++r) {
      mnew[r]  = fmaxf(mrow[r], mx[r]);
      alpha[r] = __expf(mrow[r] - mnew[r]);
      rs[r] = 0.f;
    }
#pragma unroll
    for (int nt = 0; nt < 4; ++nt)
#pragma unroll
      for (int r = 0; r < 4; ++r) {
        float p = __expf(s[nt][r] - mnew[r]);
        s[nt][r] = p;
        rs[r] += p;
      }
#pragma unroll
    for (int m = 1; m <= 8; m <<= 1)
#pragma unroll
      for (int r = 0; r < 4; ++r) rs[r] += __shfl_xor(rs[r], m);
#pragma unroll
    for (int r = 0; r < 4; ++r) {
      lrow[r] = lrow[r] * alpha[r] + rs[r];
      mrow[r] = mnew[r];
    }
#pragma unroll
    for (int ht = 0; ht < 4; ++ht)
#pragma unroll
      for (int r = 0; r < 4; ++r) O[ht][r] *= alpha[r];

#pragma unroll
    for (int nt = 0; nt < 4; ++nt)
#pragma unroll
      for (int r = 0; r < 4; ++r)
        pw[(quad * 4 + r) * 72 + nt * 16 + col] = (f16)s[nt][r];
    const f16* pr = pw + col * 72 + quad * 8;
    f16x8 p0 = *(const f16x8*)pr;
    f16x8 p1 = *(const f16x8*)(pr + 32);
#pragma unroll
    for (int ht = 0; ht < 4; ++ht) {
      const f16* vb = Vt + (ht * 16 + col) * 72 + quad * 8;
      f16x8 v0 = *(const f16x8*)vb;
      f16x8 v1 = *(const f16x8*)(vb + 32);
      O[ht] = __builtin_amdgcn_mfma_f32_16x16x32_f16(p0, v0, O[ht], 0, 0, 0);
      O[ht] = __builtin_amdgcn_mfma_f32_16x16x32_f16(p1, v1, O[ht], 0, 0, 0);
    }
    __syncthreads();
  }

#pragma unroll
  for (int ht = 0; ht < 4; ++ht)
#pragma unroll
    for (int r = 0; r < 4; ++r) {
      int row = q0 + w * 16 + quad * 4 + r;
      int cg = head * HD_ + ht * 16 + col;
      ctx[(size_t)row * H_ + cg] = (f16)(O[ht][r] / lrow[r]);
    }
}

// ---------------------------------------------------------------------------
extern "C" void kernel_launch(void* const* d_in, const int* in_sizes, int n_in,
                              void* d_out, int out_size, void* d_ws, size_t ws_size,
                              hipStream_t stream) {
  const void* embeds = d_in[0];
  const void* Wq = d_in[2];
  const void* Wk = d_in[3];
  const void* Wv = d_in[4];
  const void* Wo = d_in[5];
  const void* bo = d_in[6];
  const void* W1 = d_in[7];
  const void* W2 = d_in[8];
  const void* b2 = d_in[9];
  const void* g1 = d_in[10];
  const void* g2 = d_in[11];
  const void* gf = d_in[12];
  const unsigned int* probe = (const unsigned int*)g1;

  char* W = (char*)d_ws;
  float* xf  = (float*)(W);                       // 16 MB fp32 residual
  f16* hbuf  = (f16*)(W + (16ull << 20));         //  8 MB LN output
  f16* qkvb  = (f16*)(W + (24ull << 20));         // 24 MB fused q|k|v (attn)
  f16* ctxb  = (f16*)(W + (48ull << 20));         //  8 MB attention out
  f16* m1b   = (f16*)(W + (24ull << 20));         // 32 MB MLP mid (aliases)
  f16* Wt    = (f16*)(W + (56ull << 20));         // 32 MB transposed weight
  (void)in_sizes; (void)n_in; (void)out_size; (void)ws_size;

  embed2f_k<<<S_ * H_ / 1024, 256, 0, stream>>>(embeds, xf, probe);

  for (int l = 0; l < L_; ++l) {
    size_t wo = (size_t)l * H_ * H_;
    // --- attention block ---
    ln_k<0><<<S_, 256, 0, stream>>>(xf, g1, (size_t)l * H_, hbuf, probe);
    transp_k<<<dim3(H_ / 64, H_ / 64), 256, 0, stream>>>(Wq, wo, Wt, H_, H_, probe);
    transp_k<<<dim3(H_ / 64, H_ / 64), 256, 0, stream>>>(Wk, wo, Wt + (size_t)H_ * H_, H_, H_, probe);
    transp_k<<<dim3(H_ / 64, H_ / 64), 256, 0, stream>>>(Wv, wo, Wt + 2ull * H_ * H_, H_, H_, probe);
    gemm256_k<0><<<dim3(S_ / 256, 3 * H_ / 256), 512, 0, stream>>>(hbuf, Wt, qkvb, nullptr, nullptr, 0, 3 * H_, H_, probe);
    attn_k<<<dim3(S_ / 64, NH_), 256, 0, stream>>>(qkvb, ctxb);
    transp_k<<<dim3(H_ / 64, H_ / 64), 256, 0, stream>>>(Wo, wo, Wt, H_, H_, probe);
    gemm256_k<2><<<dim3(S_ / 256, H_ / 256, 4), 512, 0, stream>>>(ctxb, Wt, nullptr, xf, bo, (size_t)l * H_, H_, H_, probe);
    // --- MLP block ---
    ln_k<0><<<S_, 256, 0, stream>>>(xf, g2, (size_t)l * H_, hbuf, probe);
    transp_k<<<dim3(I_ / 64, H_ / 64), 256, 0, stream>>>(W1, (size_t)l * H_ * I_, Wt, H_, I_, probe);
    gemm256_k<1><<<dim3(S_ / 256, I_ / 256), 512, 0, stream>>>(hbuf, Wt, m1b, nullptr, nullptr, 0, I_, H_, probe);
    transp_k<<<dim3(H_ / 64, I_ / 64), 256, 0, stream>>>(W2, (size_t)l * I_ * H_, Wt, I_, H_, probe);
    gemm256_k<2><<<dim3(S_ / 256, H_ / 256, 4), 512, 0, stream>>>(m1b, Wt, nullptr, xf, b2, (size_t)l * H_, H_, I_, probe);
  }
  ln_k<1><<<S_, 256, 0, stream>>>(xf, gf, 0, d_out, probe);
}

// Round 3
// 1438.678 us; speedup vs baseline: 1.0740x; 1.0581x over previous
//
#include <hip/hip_runtime.h>
#include <hip/hip_bf16.h>
#include <stdint.h>

// ---------------------------------------------------------------------------
// Phi3-style transformer forward, MI355X round 4.
// B=1 S=2048 H=2048 NH=32 HD=64 I=8192 L=2.
// Round-4 change: attn_k rewritten (was 171us @ 4% MfmaUtil, 20M bank
// conflicts, 2 barriers/chunk, no staging overlap):
//   - 512 threads / 8 waves, 128 q-rows per block (grid 512)
//   - double-buffered K/V, chunk c+1 staged while computing chunk c,
//     ONE barrier per chunk (T14 async-stage split)
//   - K staged via global_load_lds, XOR-granule swizzle (rule 21):
//     conflict-free ds_read_b128, no VGPR round-trip
// Also: gemm256 MODE2 N-tile rotated by blockIdx.z (stagger split-K atomics).
// ---------------------------------------------------------------------------

#define H_   2048
#define NH_  32
#define HD_  64
#define I_   8192
#define L_   2
#define S_   2048
#define EPS_ 1e-5f

typedef _Float16 f16;
typedef __attribute__((ext_vector_type(8))) _Float16 f16x8;
typedef __attribute__((ext_vector_type(4))) float   f32x4;

#define BF16_PROBE 0x3F803F80u

static __device__ __forceinline__ float bf2f(unsigned short b) {
  return __uint_as_float(((unsigned int)b) << 16);
}

static __device__ __forceinline__ float gelu_f(float x) {
  float y = 0.7978845608028654f * x * (1.0f + 0.044715f * x * x);
  return x / (1.0f + __expf(-2.0f * y));
}

// async global->LDS, 16B per lane.  LDS dest must be wave-base + lane*16.
#define GLDS(gp, lp)                                                          \
  __builtin_amdgcn_global_load_lds(                                           \
      (const __attribute__((address_space(1))) unsigned int*)(gp),            \
      (__attribute__((address_space(3))) unsigned int*)(lp), 16, 0, 0)

// ---------------------------------------------------------------------------
// embeds (bf16 or fp32 per probe) -> fp32 residual
__global__ __launch_bounds__(256) void embed2f_k(const void* __restrict__ e,
                                                 float* __restrict__ xf,
                                                 const unsigned int* __restrict__ probe) {
  bool isbf = (*probe == BF16_PROBE);
  int i = (blockIdx.x * 256 + threadIdx.x) * 4;
  float4 o;
  if (isbf) {
    uint2 d = *(const uint2*)((const unsigned short*)e + i);
    o.x = bf2f((unsigned short)(d.x & 0xffff));
    o.y = bf2f((unsigned short)(d.x >> 16));
    o.z = bf2f((unsigned short)(d.y & 0xffff));
    o.w = bf2f((unsigned short)(d.y >> 16));
  } else {
    o = *(const float4*)((const float*)e + i);
  }
  *(float4*)(xf + i) = o;
}

// ---------------------------------------------------------------------------
// LayerNorm (mean-subtract, var-normalize, *gamma, no beta) over H=2048.
template <int OUT_FINAL>
__global__ __launch_bounds__(256) void ln_k(const float* __restrict__ x,
                                            const void* __restrict__ gammav,
                                            size_t geoff,
                                            void* __restrict__ outv,
                                            const unsigned int* __restrict__ probe) {
  bool isbf = (*probe == BF16_PROBE);
  int row = blockIdx.x, t = threadIdx.x;
  const float* xr = x + (size_t)row * H_;
  float4 a = ((const float4*)xr)[t];
  float4 b = ((const float4*)xr)[t + 256];
  float s  = a.x + a.y + a.z + a.w + b.x + b.y + b.z + b.w;
  float ss = a.x*a.x + a.y*a.y + a.z*a.z + a.w*a.w
           + b.x*b.x + b.y*b.y + b.z*b.z + b.w*b.w;
#pragma unroll
  for (int m = 32; m >= 1; m >>= 1) { s += __shfl_xor(s, m); ss += __shfl_xor(ss, m); }
  __shared__ float red[8];
  if ((t & 63) == 0) { red[t >> 6] = s; red[4 + (t >> 6)] = ss; }
  __syncthreads();
  s  = red[0] + red[1] + red[2] + red[3];
  ss = red[4] + red[5] + red[6] + red[7];
  float mu   = s * (1.0f / H_);
  float rstd = rsqrtf(ss * (1.0f / H_) - mu * mu + EPS_);
  float va[8] = {a.x, a.y, a.z, a.w, b.x, b.y, b.z, b.w};
#pragma unroll
  for (int hh = 0; hh < 2; ++hh) {
    int cbase = (hh == 0) ? t * 4 : (t + 256) * 4;
#pragma unroll
    for (int j = 0; j < 4; ++j) {
      int c = cbase + j;
      float g = isbf ? bf2f(((const unsigned short*)gammav)[geoff + c])
                     : ((const float*)gammav)[geoff + c];
      float o = (va[hh * 4 + j] - mu) * rstd * g;
      size_t idx = (size_t)row * H_ + c;
      if (OUT_FINAL) {
        if (isbf) ((__hip_bfloat16*)outv)[idx] = __float2bfloat16(o);
        else      ((float*)outv)[idx] = o;
      } else {
        ((f16*)outv)[idx] = (f16)o;
      }
    }
  }
}

// ---------------------------------------------------------------------------
// Transpose + convert: W[R,C] (bf16|fp32) -> Wt[C,R] f16.  64x64 tiles.
__global__ __launch_bounds__(256) void transp_k(const void* __restrict__ in,
                                                size_t eoff,
                                                f16* __restrict__ out, int R, int C,
                                                const unsigned int* __restrict__ probe) {
  bool isbf = (*probe == BF16_PROBE);
  __shared__ __attribute__((aligned(16))) f16 tile[64][72];  // +8 pad
  int t = threadIdx.x;
  int r0 = blockIdx.y * 64, c0 = blockIdx.x * 64;
#pragma unroll
  for (int it = 0; it < 2; ++it) {
    int idx = it * 256 + t;
    int r = idx >> 3, c8 = (idx & 7) * 8;
    size_t goff = eoff + (size_t)(r0 + r) * C + c0 + c8;
    if (isbf) {
      uint4 d = *(const uint4*)((const unsigned short*)in + goff);  // 8 bf16
      unsigned int dw[4] = {d.x, d.y, d.z, d.w};
#pragma unroll
      for (int p = 0; p < 4; ++p) {
        tile[r][c8 + 2 * p]     = (f16)bf2f((unsigned short)(dw[p] & 0xffff));
        tile[r][c8 + 2 * p + 1] = (f16)bf2f((unsigned short)(dw[p] >> 16));
      }
    } else {
      float4 fa = *(const float4*)((const float*)in + goff);
      float4 fb = *(const float4*)((const float*)in + goff + 4);
      tile[r][c8 + 0] = (f16)fa.x; tile[r][c8 + 1] = (f16)fa.y;
      tile[r][c8 + 2] = (f16)fa.z; tile[r][c8 + 3] = (f16)fa.w;
      tile[r][c8 + 4] = (f16)fb.x; tile[r][c8 + 5] = (f16)fb.y;
      tile[r][c8 + 6] = (f16)fb.z; tile[r][c8 + 7] = (f16)fb.w;
    }
  }
  __syncthreads();
#pragma unroll
  for (int it = 0; it < 2; ++it) {
    int idx = it * 256 + t;
    int rn = idx >> 3, k8 = (idx & 7) * 8;
    f16x8 o;
#pragma unroll
    for (int j = 0; j < 8; ++j) o[j] = tile[k8 + j][rn];
    *(f16x8*)(out + (size_t)(c0 + rn) * R + r0 + k8) = o;
  }
}

// ---------------------------------------------------------------------------
// GEMM 256x256, BK=64, 8 waves (2Mx4N), 8-phase counted-vmcnt schedule.
// LDS 128 KiB: [buf2][A|B][256][64] f16, 16B-granule XOR swizzle g^=(row&7)
// Staging schedule: ph0: A0(u+1)  ph1: A1(u+1)  ph2: B0(u+2)  ph3: B1(u+2)
// Boundary wait once per K-tile at ph3: vmcnt(4) (2 half-tiles in flight).
// MODE 0: store f16.  MODE 1: gelu -> f16.
// MODE 2: split-K partial; atomicAdd into fp32 residual (+bias on split 0).
//         N-tile rotated by blockIdx.z to stagger atomic arrivals.
// Requires: M%256==0, N%256==0, (K/gridDim.z)%64==0, (K/gridDim.z)/64 >= 2.

#define MIDBAR()                                                              \
  asm volatile("" ::: "memory");                                              \
  __builtin_amdgcn_s_barrier();                                               \
  asm volatile("s_waitcnt lgkmcnt(0)" ::: "memory");                          \
  __builtin_amdgcn_sched_barrier(0);                                          \
  __builtin_amdgcn_s_setprio(1)

#define ENDBAR()                                                              \
  asm volatile("" ::: "memory");                                              \
  __builtin_amdgcn_s_barrier();                                               \
  __builtin_amdgcn_sched_barrier(0)

#define LDA8(AF, BUF, MH)                                                     \
  _Pragma("unroll") for (int m2 = 0; m2 < 4; ++m2)                            \
  _Pragma("unroll") for (int kk = 0; kk < 2; ++kk)                            \
    AF[m2][kk] = *(const f16x8*)(lds + (BUF) * 32768 +                        \
        (wr * 128 + (MH) * 64 + m2 * 16 + col) * 64 +                         \
        ((((kk << 2) + quad) ^ xq) << 3));

#define LDB4(BF, BUF, NH)                                                     \
  _Pragma("unroll") for (int n2 = 0; n2 < 2; ++n2)                            \
  _Pragma("unroll") for (int kk = 0; kk < 2; ++kk)                            \
    BF[n2][kk] = *(const f16x8*)(lds + 16384 + (BUF) * 32768 +                \
        (wc * 64 + (NH) * 32 + n2 * 16 + col) * 64 +                         \
        ((((kk << 2) + quad) ^ xq) << 3));

#define QMM(AF, BF, MH, NH)                                                   \
  _Pragma("unroll") for (int m2 = 0; m2 < 4; ++m2)                            \
  _Pragma("unroll") for (int n2 = 0; n2 < 2; ++n2)                            \
  _Pragma("unroll") for (int kk = 0; kk < 2; ++kk)                            \
    acc[(MH) * 4 + m2][(NH) * 2 + n2] =                                       \
        __builtin_amdgcn_mfma_f32_16x16x32_f16(                               \
            AF[m2][kk], BF[n2][kk], acc[(MH) * 4 + m2][(NH) * 2 + n2], 0, 0, 0);

template <int MODE>
__global__ __launch_bounds__(512, 2) void gemm256_k(const f16* __restrict__ A,
                                                    const f16* __restrict__ Bt,
                                                    f16* __restrict__ Cf,
                                                    float* __restrict__ xres,
                                                    const void* __restrict__ biasv,
                                                    size_t beoff,
                                                    int N, int K,
                                                    const unsigned int* __restrict__ probe) {
  __shared__ __attribute__((aligned(16))) f16 lds[65536];  // 128 KiB
  const int t = threadIdx.x;
  const int lane = t & 63, wid = t >> 6;
  const int col = lane & 15, quad = lane >> 4;
  const int xq = lane & 7;
  const int wr = wid >> 2, wc = wid & 3;  // 2M x 4N waves
  const int tm = blockIdx.x * 256;
  int yy = (int)blockIdx.y + (int)blockIdx.z;          // rotate N-tile by split
  if (yy >= (int)gridDim.y) yy -= (int)gridDim.y;      // (identity if z==0)
  const int tn = yy * 256;
  const int KSP = K / (int)gridDim.z;       // K-range per split
  const int kb  = (int)blockIdx.z * KSP;    // this split's K offset
  const int NK  = KSP >> 6;

  f32x4 acc[8][4];
#pragma unroll
  for (int i = 0; i < 8; ++i)
#pragma unroll
    for (int j = 0; j < 4; ++j) acc[i][j] = (f32x4){0.f, 0.f, 0.f, 0.f};

  // per-thread staging geometry (inverse-swizzled source granule)
  const int srow = t >> 3;                       // 0..63
  const int gs   = (t & 7) ^ (srow & 7);         // inverse-swizzled src granule
  const f16* gA = A  + (size_t)(tm + srow) * K + kb + gs * 8;
  const f16* gB = Bt + (size_t)(tn + srow) * K + kb + gs * 8;
  f16* lbase = lds + t * 8;

  // stage half-tile (mat: 0=A 1=B, half h) of K-tile u; 2 x GLDS per thread
  auto STAGE = [&](int mat, int h, int u) {
    if (u >= NK) return;
    const f16* gp0 = (mat ? gB : gA) + (size_t)(h * 128) * K + u * 64;
    f16* lp = lbase + (u & 1) * 32768 + mat * 16384 + h * 8192;
    GLDS(gp0, lp);
    GLDS(gp0 + (size_t)64 * K, lp + 4096);
  };

  // prologue: B0(0),B1(0),A0(0),A1(0),B0(1),B1(1); tile0 resident after wait
  STAGE(1, 0, 0); STAGE(1, 1, 0); STAGE(0, 0, 0); STAGE(0, 1, 0);
  STAGE(1, 0, 1); STAGE(1, 1, 1);
  asm volatile("s_waitcnt vmcnt(4)" ::: "memory");
  __builtin_amdgcn_s_barrier();
  __builtin_amdgcn_sched_barrier(0);

  f16x8 afr[4][2], b0f[2][2], b1f[2][2];

  for (int u = 0; u < NK; ++u) {
    const int b = u & 1;
    // ---- phase 0: Q(0,0); reads A-mh0 (8) + B-nh0 (4); stage A0(u+1)
    LDA8(afr, b, 0);
    LDB4(b0f, b, 0);
    STAGE(0, 0, u + 1);
    MIDBAR();
    QMM(afr, b0f, 0, 0);
    __builtin_amdgcn_s_setprio(0);
    ENDBAR();
    // ---- phase 1: Q(0,1); reads B-nh1 (4); stage A1(u+1)
    LDB4(b1f, b, 1);
    STAGE(0, 1, u + 1);
    MIDBAR();
    QMM(afr, b1f, 0, 1);
    __builtin_amdgcn_s_setprio(0);
    ENDBAR();
    // ---- phase 2: Q(1,1); reads A-mh1 (8); stage B0(u+2)
    LDA8(afr, b, 1);
    STAGE(1, 0, u + 2);
    MIDBAR();
    QMM(afr, b1f, 1, 1);
    __builtin_amdgcn_s_setprio(0);
    ENDBAR();
    // ---- phase 3: Q(1,0); no reads (b0f kept in regs); stage B1(u+2)
    STAGE(1, 1, u + 2);
    MIDBAR();
    QMM(afr, b0f, 1, 0);
    __builtin_amdgcn_s_setprio(0);
    if (u + 2 < NK) { asm volatile("s_waitcnt vmcnt(4)" ::: "memory"); }
    else            { asm volatile("s_waitcnt vmcnt(0)" ::: "memory"); }
    ENDBAR();
  }

  // epilogue: C/D layout col=lane&15, row=quad*4+reg (m89/m91 verified)
  bool isbf = false;
  if (MODE == 2) isbf = (*probe == BF16_PROBE);
  const bool addb = (MODE == 2) && (blockIdx.z == 0);
#pragma unroll
  for (int m = 0; m < 8; ++m) {
    int row = tm + wr * 128 + m * 16 + quad * 4;
#pragma unroll
    for (int n = 0; n < 4; ++n) {
      int cg = tn + wc * 64 + n * 16 + col;
#pragma unroll
      for (int r = 0; r < 4; ++r) {
        float v = acc[m][n][r];
        if (MODE == 1) v = gelu_f(v);
        size_t idx = (size_t)(row + r) * N + cg;
        if (MODE <= 1) {
          Cf[idx] = (f16)v;
        } else {
          if (addb) {
            v += isbf ? bf2f(((const unsigned short*)biasv)[beoff + cg])
                      : ((const float*)biasv)[beoff + cg];
          }
          atomicAdd(xres + idx, v);
        }
      }
    }
  }
}

// ---------------------------------------------------------------------------
// Fused causal flash attention, round-4 structure.
// qkv:[S, 3H] f16 (q|k|v per row, head-major cols).
// Block: 512 threads / 8 waves, 128 q-rows (wave w owns rows q0+w*16..+15).
// Grid: (S/128, NH), q-tiles reversed (heavy first).
// K: double-buffered LDS via global_load_lds, XOR-granule swizzle
//    (linear dest + inverse-swizzled global source, rule 21) -> conflict-free
//    ds_read_b128 at stride 128B.
// V: global->reg load issued one chunk ahead; transpose-write into padded
//    Vt[hd][key] after compute (T14 async-stage split).
// One __syncthreads per chunk.
__global__ __launch_bounds__(512) void attn_k(const f16* __restrict__ qkv,
                                              f16* __restrict__ ctx) {
  __shared__ __attribute__((aligned(16))) f16 Ks[2][64 * 64];   // swizzled
  __shared__ __attribute__((aligned(16))) f16 Vt[2][64 * 72];   // [hd][key]+pad
  __shared__ __attribute__((aligned(16))) f16 Ps[8][16 * 72];   // per-wave P
  const int RS = 3 * H_;  // 6144
  int t = threadIdx.x, w = t >> 6, lane = t & 63;
  int col = lane & 15, quad = lane >> 4;
  int head = blockIdx.y;
  int qb = (gridDim.x - 1) - blockIdx.x;  // reversed: heavy tiles first
  int q0 = qb * 128;
  const int NC = qb * 2 + 2;              // chunks of 64 keys

  // q A-fragments (regs): m=col, k=quad*8+j (+32 for qf1)
  int qrow = q0 + w * 16 + col;
  const f16* qp = qkv + (size_t)qrow * RS + head * HD_ + quad * 8;
  f16x8 qf0 = *(const f16x8*)qp;
  f16x8 qf1 = *(const f16x8*)(qp + 32);

  // staging geometry: thread t covers key r = t>>3, granule g = t&7
  const int sr = t >> 3, sg = t & 7;
  const f16* kgp = qkv + (size_t)sr * RS + H_ + head * HD_ + ((sg ^ (sr & 7)) * 8);
  const f16* vgp = qkv + (size_t)sr * RS + 2 * H_ + head * HD_ + sg * 8;
  f16* klp = &Ks[0][0] + t * 8;  // linear dest (wave-base + lane*16B)

  f32x4 O[4];
#pragma unroll
  for (int ht = 0; ht < 4; ++ht) O[ht] = (f32x4){0.f, 0.f, 0.f, 0.f};
  f32x4 mrow = (f32x4){-1e30f, -1e30f, -1e30f, -1e30f};
  f32x4 lrow = (f32x4){0.f, 0.f, 0.f, 0.f};
  f16* pw = &Ps[w][0];

  // prologue: stage chunk 0 into buffer 0
  GLDS(kgp, klp);
  f16x8 vv = *(const f16x8*)vgp;
#pragma unroll
  for (int j = 0; j < 8; ++j) Vt[0][(sg * 8 + j) * 72 + sr] = vv[j];
  __syncthreads();  // implicit vmcnt(0): K glds + Vt writes visible

  for (int c = 0; c < NC; ++c) {
    const int b = c & 1;
    // issue next chunk's loads (latency hides under compute of chunk c)
    if (c + 1 < NC) {
      size_t roff = (size_t)(c + 1) * 64 * RS;
      GLDS(kgp + roff, klp + (1 - b) * 64 * 64);
      vv = *(const f16x8*)(vgp + roff);
    }

    const bool active = (c * 64 <= q0 + w * 16 + 15);
    if (active) {
      int k0 = c * 64;
      // S = q . K^T : 4 key-tiles of 16, k-dim 64 = 2 MFMAs each
      f32x4 s[4];
#pragma unroll
      for (int nt = 0; nt < 4; ++nt) {
        int key = nt * 16 + col;
        const f16* kb0 = &Ks[b][key * 64 + ((quad ^ (key & 7)) * 8)];
        const f16* kb1 = &Ks[b][key * 64 + (((quad + 4) ^ (key & 7)) * 8)];
        f16x8 b0 = *(const f16x8*)kb0;
        f16x8 b1 = *(const f16x8*)kb1;
        f32x4 z = (f32x4){0.f, 0.f, 0.f, 0.f};
        z = __builtin_amdgcn_mfma_f32_16x16x32_f16(qf0, b0, z, 0, 0, 0);
        z = __builtin_amdgcn_mfma_f32_16x16x32_f16(qf1, b1, z, 0, 0, 0);
        s[nt] = z;
      }
      // scale + causal mask
      int rq = q0 + w * 16 + quad * 4;
#pragma unroll
      for (int nt = 0; nt < 4; ++nt)
#pragma unroll
        for (int r = 0; r < 4; ++r) {
          float sv = s[nt][r] * 0.125f;
          if (k0 + nt * 16 + col > rq + r) sv = -1e30f;
          s[nt][r] = sv;
        }
      // online softmax (row stats replicated across 16-lane col group)
      f32x4 mx;
#pragma unroll
      for (int r = 0; r < 4; ++r)
        mx[r] = fmaxf(fmaxf(s[0][r], s[1][r]), fmaxf(s[2][r], s[3][r]));
#pragma unroll
      for (int m = 1; m <= 8; m <<= 1)
#pragma unroll
        for (int r = 0; r < 4; ++r) mx[r] = fmaxf(mx[r], __shfl_xor(mx[r], m));
      f32x4 mnew, alpha, rs;
#pragma unroll
      for (int r = 0; r < 4; ++r) {
        mnew[r]  = fmaxf(mrow[r], mx[r]);
        alpha[r] = __expf(mrow[r] - mnew[r]);
        rs[r] = 0.f;
      }
#pragma unroll
      for (int nt = 0; nt < 4; ++nt)
#pragma unroll
        for (int r = 0; r < 4; ++r) {
          float p = __expf(s[nt][r] - mnew[r]);
          s[nt][r] = p;
          rs[r] += p;
        }
#pragma unroll
      for (int m = 1; m <= 8; m <<= 1)
#pragma unroll
        for (int r = 0; r < 4; ++r) rs[r] += __shfl_xor(rs[r], m);
#pragma unroll
      for (int r = 0; r < 4; ++r) {
        lrow[r] = lrow[r] * alpha[r] + rs[r];
        mrow[r] = mnew[r];
      }
#pragma unroll
      for (int ht = 0; ht < 4; ++ht)
#pragma unroll
        for (int r = 0; r < 4; ++r) O[ht][r] *= alpha[r];

      // P: C-layout -> LDS -> A-layout (wave-private; same-wave DS in-order)
#pragma unroll
      for (int nt = 0; nt < 4; ++nt)
#pragma unroll
        for (int r = 0; r < 4; ++r)
          pw[(quad * 4 + r) * 72 + nt * 16 + col] = (f16)s[nt][r];
      const f16* pr = pw + col * 72 + quad * 8;
      f16x8 p0 = *(const f16x8*)pr;
      f16x8 p1 = *(const f16x8*)(pr + 32);
      // O += P . V
#pragma unroll
      for (int ht = 0; ht < 4; ++ht) {
        const f16* vb = &Vt[b][(ht * 16 + col) * 72 + quad * 8];
        f16x8 v0 = *(const f16x8*)vb;
        f16x8 v1 = *(const f16x8*)(vb + 32);
        O[ht] = __builtin_amdgcn_mfma_f32_16x16x32_f16(p0, v0, O[ht], 0, 0, 0);
        O[ht] = __builtin_amdgcn_mfma_f32_16x16x32_f16(p1, v1, O[ht], 0, 0, 0);
      }
    }

    // late V transpose-write for chunk c+1 (vv auto-waited here)
    if (c + 1 < NC) {
#pragma unroll
      for (int j = 0; j < 8; ++j) Vt[1 - b][(sg * 8 + j) * 72 + sr] = vv[j];
    }
    __syncthreads();  // drains K glds(c+1); Vt(c+1) visible; buf reuse safe
  }

  // epilogue: ctx[row, head*64+hd] = O / l
#pragma unroll
  for (int ht = 0; ht < 4; ++ht)
#pragma unroll
    for (int r = 0; r < 4; ++r) {
      int row = q0 + w * 16 + quad * 4 + r;
      int cg = head * HD_ + ht * 16 + col;
      ctx[(size_t)row * H_ + cg] = (f16)(O[ht][r] / lrow[r]);
    }
}

// ---------------------------------------------------------------------------
extern "C" void kernel_launch(void* const* d_in, const int* in_sizes, int n_in,
                              void* d_out, int out_size, void* d_ws, size_t ws_size,
                              hipStream_t stream) {
  const void* embeds = d_in[0];
  const void* Wq = d_in[2];
  const void* Wk = d_in[3];
  const void* Wv = d_in[4];
  const void* Wo = d_in[5];
  const void* bo = d_in[6];
  const void* W1 = d_in[7];
  const void* W2 = d_in[8];
  const void* b2 = d_in[9];
  const void* g1 = d_in[10];
  const void* g2 = d_in[11];
  const void* gf = d_in[12];
  const unsigned int* probe = (const unsigned int*)g1;

  char* W = (char*)d_ws;
  float* xf  = (float*)(W);                       // 16 MB fp32 residual
  f16* hbuf  = (f16*)(W + (16ull << 20));         //  8 MB LN output
  f16* qkvb  = (f16*)(W + (24ull << 20));         // 24 MB fused q|k|v (attn)
  f16* ctxb  = (f16*)(W + (48ull << 20));         //  8 MB attention out
  f16* m1b   = (f16*)(W + (24ull << 20));         // 32 MB MLP mid (aliases)
  f16* Wt    = (f16*)(W + (56ull << 20));         // 32 MB transposed weight
  (void)in_sizes; (void)n_in; (void)out_size; (void)ws_size;

  embed2f_k<<<S_ * H_ / 1024, 256, 0, stream>>>(embeds, xf, probe);

  for (int l = 0; l < L_; ++l) {
    size_t wo = (size_t)l * H_ * H_;
    // --- attention block ---
    ln_k<0><<<S_, 256, 0, stream>>>(xf, g1, (size_t)l * H_, hbuf, probe);
    transp_k<<<dim3(H_ / 64, H_ / 64), 256, 0, stream>>>(Wq, wo, Wt, H_, H_, probe);
    transp_k<<<dim3(H_ / 64, H_ / 64), 256, 0, stream>>>(Wk, wo, Wt + (size_t)H_ * H_, H_, H_, probe);
    transp_k<<<dim3(H_ / 64, H_ / 64), 256, 0, stream>>>(Wv, wo, Wt + 2ull * H_ * H_, H_, H_, probe);
    gemm256_k<0><<<dim3(S_ / 256, 3 * H_ / 256), 512, 0, stream>>>(hbuf, Wt, qkvb, nullptr, nullptr, 0, 3 * H_, H_, probe);
    attn_k<<<dim3(S_ / 128, NH_), 512, 0, stream>>>(qkvb, ctxb);
    transp_k<<<dim3(H_ / 64, H_ / 64), 256, 0, stream>>>(Wo, wo, Wt, H_, H_, probe);
    gemm256_k<2><<<dim3(S_ / 256, H_ / 256, 4), 512, 0, stream>>>(ctxb, Wt, nullptr, xf, bo, (size_t)l * H_, H_, H_, probe);
    // --- MLP block ---
    ln_k<0><<<S_, 256, 0, stream>>>(xf, g2, (size_t)l * H_, hbuf, probe);
    transp_k<<<dim3(I_ / 64, H_ / 64), 256, 0, stream>>>(W1, (size_t)l * H_ * I_, Wt, H_, I_, probe);
    gemm256_k<1><<<dim3(S_ / 256, I_ / 256), 512, 0, stream>>>(hbuf, Wt, m1b, nullptr, nullptr, 0, I_, H_, probe);
    transp_k<<<dim3(H_ / 64, I_ / 64), 256, 0, stream>>>(W2, (size_t)l * I_ * H_, Wt, I_, H_, probe);
    gemm256_k<2><<<dim3(S_ / 256, H_ / 256, 4), 512, 0, stream>>>(m1b, Wt, nullptr, xf, b2, (size_t)l * H_, H_, I_, probe);
  }
  ln_k<1><<<S_, 256, 0, stream>>>(xf, gf, 0, d_out, probe);
}